// Round 7
// baseline (362.174 us; speedup 1.0000x reference)
//
#include <hip/hip_runtime.h>

#define Bq 2
#define Nn 6
#define Dd 48
#define Hh 28
#define Ww 60
#define Cc 64
#define Xd 200
#define Yd 200
#define NP (Nn*Dd*Hh*Ww)      // 483840 points per batch
#define TOTP (Bq*NP)          // 967680 total points
#define NVOX (Xd*Yd)          // 40000 voxels per batch (Z=1)
#define NSEG (Bq*NVOX)        // 80000 segments
#define NB1  79               // ceil(NSEG/1024)
#define CAP  512              // staged point-ids per wave (avg need ~66)

// Zero the histogram ourselves: rocclr fillBufferAligned is pathologically slow
__global__ __launch_bounds__(1024) void zero_cnt(int* __restrict__ cnt)
{
    int i = blockIdx.x * 1024 + threadIdx.x;
    if (i < NSEG) cnt[i] = 0;
}

// ---------------------------------------------------------------------------
// Phase A: voxelize each point, store segment id (-1 invalid), histogram count
// ---------------------------------------------------------------------------
__global__ __launch_bounds__(256) void phase_a(
    const float* __restrict__ geom, int* __restrict__ rank, int* __restrict__ cnt)
{
    int p = blockIdx.x * 256 + threadIdx.x;
    if (p >= TOTP) return;
    float gx = geom[(long)p*3 + 0];
    float gy = geom[(long)p*3 + 1];
    float gz = geom[(long)p*3 + 2];
    // must match numpy astype(int32): truncate toward zero, f32 arithmetic
    int vx = (int)((gx + 50.0f) / 0.5f);
    int vy = (int)((gy + 50.0f) / 0.5f);
    int vz = (int)((gz + 10.0f) / 20.0f);
    int seg = -1;
    if (vx >= 0 && vx < Xd && vy >= 0 && vy < Yd && vz == 0) {
        int b = (p >= NP) ? 1 : 0;
        seg = b * NVOX + vx * Yd + vy;
        atomicAdd(&cnt[seg], 1);
    }
    rank[p] = seg;
}

// Scan P1: per-1024-block exclusive scan of cnt -> start, block totals -> bsum
__global__ __launch_bounds__(1024) void scan_p1(
    const int* __restrict__ cnt, int* __restrict__ start, int* __restrict__ bsum)
{
    __shared__ int sh[1024];
    int tid = threadIdx.x;
    int i = blockIdx.x * 1024 + tid;
    int v = (i < NSEG) ? cnt[i] : 0;
    sh[tid] = v;
    __syncthreads();
    for (int off = 1; off < 1024; off <<= 1) {
        int t = (tid >= off) ? sh[tid - off] : 0;
        __syncthreads();
        sh[tid] += t;
        __syncthreads();
    }
    if (i < NSEG) start[i] = sh[tid] - v;
    if (tid == 1023) bsum[blockIdx.x] = sh[1023];
}

// Scan P2: exclusive scan of block totals (single block)
__global__ __launch_bounds__(128) void scan_p2(int* __restrict__ bsum)
{
    __shared__ int sh[128];
    int tid = threadIdx.x;
    int v = (tid < NB1) ? bsum[tid] : 0;
    sh[tid] = v;
    __syncthreads();
    for (int off = 1; off < 128; off <<= 1) {
        int t = (tid >= off) ? sh[tid - off] : 0;
        __syncthreads();
        sh[tid] += t;
        __syncthreads();
    }
    if (tid < NB1) bsum[tid] = sh[tid] - v;
}

// Scan P3: add block offsets
__global__ __launch_bounds__(1024) void scan_p3(
    int* __restrict__ start, const int* __restrict__ bsum)
{
    int i = blockIdx.x * 1024 + threadIdx.x;
    if (i < NSEG) start[i] += bsum[blockIdx.x];
}

// Phase C: scatter point ids into segment-ordered list; start[] becomes end[]
__global__ __launch_bounds__(256) void phase_c(
    const int* __restrict__ rank, int* __restrict__ start, int* __restrict__ order)
{
    int p = blockIdx.x * 256 + threadIdx.x;
    if (p >= TOTP) return;
    int seg = rank[p];
    if (seg < 0) return;
    int pos = atomicAdd(&start[seg], 1);
    order[pos] = p;
}

// ---------------------------------------------------------------------------
// Phase D: 32 voxels per block (8/wave). Stage the wave's contiguous order[]
// slice into LDS with each id TAGGED with its voxel-local index (bits 24+).
// Main loop is a FLAT stream over points: 4 points/instruction (16 lanes x
// float4 each), every iteration independent (no per-voxel reduce, no
// cross-lane ops) -> deep unroll keeps many gathers in flight. Accumulate
// via LDS atomicAdd (ds_add_f32) into the tile; then transpose-write
// out[b][c][xy] coalesced. No global atomics.
// ---------------------------------------------------------------------------
__global__ __launch_bounds__(256) void phase_d(
    const int* __restrict__ endp, const int* __restrict__ order,
    const float* __restrict__ x, float* __restrict__ out)
{
    __shared__ int   ord_sh[4][CAP];
    __shared__ float tile[32][68];
    int blk  = blockIdx.x;                 // 0 .. 2499
    int b    = blk / (NVOX/32);            // 1250 blocks per batch
    int xy0  = (blk % (NVOX/32)) * 32;
    int wv   = threadIdx.x >> 6;           // 0..3
    int lane = threadIdx.x & 63;
    int seg0 = b * NVOX + xy0 + wv * 8;    // this wave's first voxel

    // lane j<9 loads boundary end[seg0-1+j]; e[v]=begin of voxel v, e[v+1]=end
    int e = 0;
    if (lane < 9) {
        int idx = seg0 - 1 + lane;
        e = (idx >= 0) ? endp[idx] : 0;
    }
    int eb0 = __shfl(e,0), eb1 = __shfl(e,1), eb2 = __shfl(e,2),
        eb3 = __shfl(e,3), eb4 = __shfl(e,4), eb5 = __shfl(e,5),
        eb6 = __shfl(e,6), eb7 = __shfl(e,7), eb8 = __shfl(e,8);
    int count = eb8 - eb0;

    // zero this wave's tile rows (8 rows x 64 cols, wave-private)
    {
        int r = wv*8 + (lane >> 3);
        int c = (lane & 7) * 8;
        float4 z = make_float4(0.f, 0.f, 0.f, 0.f);
        *(float4*)&tile[r][c]     = z;
        *(float4*)&tile[r][c + 4] = z;
    }

    int g = lane >> 4;                     // point subgroup 0..3
    int q = (lane & 15) * 4;               // channel base for this lane

    if (count <= CAP) {                    // ~always (avg 66, CAP=512)
        // stage: coalesced order[] load + voxel-local tag in bits 24+
        for (int i = lane; i < count; i += 64) {
            int gi  = eb0 + i;
            int pid = order[gi];
            int v = (gi >= eb1) + (gi >= eb2) + (gi >= eb3) + (gi >= eb4)
                  + (gi >= eb5) + (gi >= eb6) + (gi >= eb7);
            ord_sh[wv][i] = pid | (v << 24);
        }
        __syncthreads();                   // LDS writes visible (zero + stage)

        // flat independent stream: 4 points per instruction
        #pragma unroll 4
        for (int i = g; i < count; i += 4) {
            int w   = ord_sh[wv][i];       // broadcast within subgroup
            int pid = w & 0xFFFFFF;
            int v   = w >> 24;
            const float4 a = *(const float4*)(x + (long)pid * Cc + q);
            float* row = &tile[wv*8 + v][q];
            atomicAdd(&row[0], a.x);
            atomicAdd(&row[1], a.y);
            atomicAdd(&row[2], a.z);
            atomicAdd(&row[3], a.w);
        }
    } else {                               // fallback: per-voxel global gather
        __syncthreads();                   // match barrier count
        for (int v = 0; v < 8; ++v) {
            int begin = __shfl(e, v);
            int endv  = __shfl(e, v + 1);
            float4 sum = make_float4(0.f, 0.f, 0.f, 0.f);
            for (int t = begin + g; t < endv; t += 4) {
                int p0 = order[t];
                const float4 a0 = *(const float4*)(x + (long)p0 * Cc + q);
                sum.x += a0.x; sum.y += a0.y; sum.z += a0.z; sum.w += a0.w;
            }
            #pragma unroll
            for (int m = 16; m <= 32; m <<= 1) {
                sum.x += __shfl_xor(sum.x, m);
                sum.y += __shfl_xor(sum.y, m);
                sum.z += __shfl_xor(sum.z, m);
                sum.w += __shfl_xor(sum.w, m);
            }
            if (g == 0) *(float4*)&tile[wv*8 + v][q] = sum;
        }
    }
    __syncthreads();

    // out[b][c][xy0+xy]: iteration s writes 8 channels x 32 xy
    float* dst = out + (long)b * Cc * NVOX + xy0;
    int xy = threadIdx.x & 31;
    int c0 = threadIdx.x >> 5;             // 0..7
    #pragma unroll
    for (int s = 0; s < 8; ++s) {
        int c = s * 8 + c0;
        dst[(long)c * NVOX + xy] = tile[xy][c];
    }
}

// ---------------------------------------------------------------------------
// Fallback (r1 atomic path) if ws is unexpectedly small
// ---------------------------------------------------------------------------
__global__ __launch_bounds__(256) void fiery_scatter_direct(
    const float* __restrict__ x, const float* __restrict__ geom,
    float* __restrict__ out)
{
    int wid  = blockIdx.x * 4 + (threadIdx.x >> 6);
    int lane = threadIdx.x & 63;
    if (wid >= TOTP) return;
    long gb = (long)wid * 3;
    float gx = geom[gb+0], gy = geom[gb+1], gz = geom[gb+2];
    int vx = (int)((gx + 50.0f) / 0.5f);
    int vy = (int)((gy + 50.0f) / 0.5f);
    int vz = (int)((gz + 10.0f) / 20.0f);
    if (!(vx >= 0 && vx < Xd && vy >= 0 && vy < Yd && vz == 0)) return;
    int b = (wid >= NP) ? 1 : 0;
    float vv = x[(long)wid * Cc + lane];
    long dst = ((long)(b * Cc + lane)) * NVOX + (vx * Yd + vy);
    atomicAdd(&out[dst], vv);
}

extern "C" void kernel_launch(void* const* d_in, const int* in_sizes, int n_in,
                              void* d_out, int out_size, void* d_ws, size_t ws_size,
                              hipStream_t stream)
{
    const float* x    = (const float*)d_in[0];
    const float* geom = (const float*)d_in[1];
    float* out = (float*)d_out;

    // ws layout: rank[TOTP] | order[TOTP] | cnt[NSEG] | start[NSEG] | bsum[128]
    size_t need = ((size_t)TOTP * 2 + (size_t)NSEG * 2 + 128) * sizeof(int);
    if (ws_size >= need) {
        int* rank  = (int*)d_ws;
        int* order = rank  + TOTP;
        int* cnt   = order + TOTP;
        int* start = cnt   + NSEG;
        int* bsum  = start + NSEG;

        zero_cnt<<<NB1, 1024, 0, stream>>>(cnt);
        phase_a<<<TOTP/256, 256, 0, stream>>>(geom, rank, cnt);
        scan_p1<<<NB1, 1024, 0, stream>>>(cnt, start, bsum);
        scan_p2<<<1, 128, 0, stream>>>(bsum);
        scan_p3<<<NB1, 1024, 0, stream>>>(start, bsum);
        phase_c<<<TOTP/256, 256, 0, stream>>>(rank, start, order);
        phase_d<<<Bq*(NVOX/32), 256, 0, stream>>>(start, order, x, out);
    } else {
        hipMemsetAsync(out, 0, (size_t)out_size * sizeof(float), stream);
        fiery_scatter_direct<<<TOTP/4, 256, 0, stream>>>(x, geom, out);
    }
}

// Round 8
// 130.232 us; speedup vs baseline: 2.7810x; 2.7810x over previous
//
#include <hip/hip_runtime.h>

#define Bq 2
#define Nn 6
#define Dd 48
#define Hh 28
#define Ww 60
#define Cc 64
#define Xd 200
#define Yd 200
#define NP (Nn*Dd*Hh*Ww)      // 483840 points per batch
#define TOTP (Bq*NP)          // 967680 total points
#define NVOX (Xd*Yd)          // 40000 voxels per batch (Z=1)
#define NSEG (Bq*NVOX)        // 80000 segments
#define NB1  79               // ceil(NSEG/1024)
#define CAP  512              // staged point-ids per wave (avg need ~66)

// Zero the histogram ourselves: rocclr fillBufferAligned is pathologically slow
__global__ __launch_bounds__(1024) void zero_cnt(int* __restrict__ cnt)
{
    int i = blockIdx.x * 1024 + threadIdx.x;
    if (i < NSEG) cnt[i] = 0;
}

// ---------------------------------------------------------------------------
// Phase A: voxelize each point, store segment id (-1 invalid), histogram count
// ---------------------------------------------------------------------------
__global__ __launch_bounds__(256) void phase_a(
    const float* __restrict__ geom, int* __restrict__ rank, int* __restrict__ cnt)
{
    int p = blockIdx.x * 256 + threadIdx.x;
    if (p >= TOTP) return;
    float gx = geom[(long)p*3 + 0];
    float gy = geom[(long)p*3 + 1];
    float gz = geom[(long)p*3 + 2];
    // must match numpy astype(int32): truncate toward zero, f32 arithmetic
    int vx = (int)((gx + 50.0f) / 0.5f);
    int vy = (int)((gy + 50.0f) / 0.5f);
    int vz = (int)((gz + 10.0f) / 20.0f);
    int seg = -1;
    if (vx >= 0 && vx < Xd && vy >= 0 && vy < Yd && vz == 0) {
        int b = (p >= NP) ? 1 : 0;
        seg = b * NVOX + vx * Yd + vy;
        atomicAdd(&cnt[seg], 1);
    }
    rank[p] = seg;
}

// Scan P1: per-1024-block exclusive scan of cnt -> start, block totals -> bsum
__global__ __launch_bounds__(1024) void scan_p1(
    const int* __restrict__ cnt, int* __restrict__ start, int* __restrict__ bsum)
{
    __shared__ int sh[1024];
    int tid = threadIdx.x;
    int i = blockIdx.x * 1024 + tid;
    int v = (i < NSEG) ? cnt[i] : 0;
    sh[tid] = v;
    __syncthreads();
    for (int off = 1; off < 1024; off <<= 1) {
        int t = (tid >= off) ? sh[tid - off] : 0;
        __syncthreads();
        sh[tid] += t;
        __syncthreads();
    }
    if (i < NSEG) start[i] = sh[tid] - v;
    if (tid == 1023) bsum[blockIdx.x] = sh[1023];
}

// Scan P2: exclusive scan of block totals (single block)
__global__ __launch_bounds__(128) void scan_p2(int* __restrict__ bsum)
{
    __shared__ int sh[128];
    int tid = threadIdx.x;
    int v = (tid < NB1) ? bsum[tid] : 0;
    sh[tid] = v;
    __syncthreads();
    for (int off = 1; off < 128; off <<= 1) {
        int t = (tid >= off) ? sh[tid - off] : 0;
        __syncthreads();
        sh[tid] += t;
        __syncthreads();
    }
    if (tid < NB1) bsum[tid] = sh[tid] - v;
}

// Scan P3: add block offsets
__global__ __launch_bounds__(1024) void scan_p3(
    int* __restrict__ start, const int* __restrict__ bsum)
{
    int i = blockIdx.x * 1024 + threadIdx.x;
    if (i < NSEG) start[i] += bsum[blockIdx.x];
}

// Phase C: scatter point ids into segment-ordered list; start[] becomes end[]
__global__ __launch_bounds__(256) void phase_c(
    const int* __restrict__ rank, int* __restrict__ start, int* __restrict__ order)
{
    int p = blockIdx.x * 256 + threadIdx.x;
    if (p >= TOTP) return;
    int seg = rank[p];
    if (seg < 0) return;
    int pos = atomicAdd(&start[seg], 1);
    order[pos] = p;
}

// add float4 a into accumulator AK iff v_ == k (compare-select, no branches)
#define ACC1(k, AK, v_, a) { bool m_ = ((v_) == (k)); \
    AK.x += m_ ? (a).x : 0.0f; AK.y += m_ ? (a).y : 0.0f; \
    AK.z += m_ ? (a).z : 0.0f; AK.w += m_ ? (a).w : 0.0f; }
#define ACC8(v_, a) \
    ACC1(0, A0, v_, a) ACC1(1, A1, v_, a) ACC1(2, A2, v_, a) ACC1(3, A3, v_, a) \
    ACC1(4, A4, v_, a) ACC1(5, A5, v_, a) ACC1(6, A6, v_, a) ACC1(7, A7, v_, a)
#define RED4(AK) { \
    AK.x += __shfl_xor(AK.x, 16); AK.y += __shfl_xor(AK.y, 16); \
    AK.z += __shfl_xor(AK.z, 16); AK.w += __shfl_xor(AK.w, 16); \
    AK.x += __shfl_xor(AK.x, 32); AK.y += __shfl_xor(AK.y, 32); \
    AK.z += __shfl_xor(AK.z, 32); AK.w += __shfl_xor(AK.w, 32); }

// ---------------------------------------------------------------------------
// Phase D: 32 voxels per block (8/wave). Stage the wave's contiguous order[]
// slice into LDS, each id tagged with its voxel-local index (bits 24+). Main
// loop is a FLAT independent stream: 4 points/instruction (16 lanes x float4),
// hand-unrolled 4-wide per subgroup -> 16 points (64 lines) in flight per
// wave. Accumulate into 8 per-lane float4 REGISTER accumulators via
// compare-select (no LDS/global atomics, no cross-lane ops in the loop).
// One shfl_xor(16,32) reduce per accumulator at the end, LDS transpose tile,
// coalesced out[b][c][xy] writes.
// ---------------------------------------------------------------------------
__global__ __launch_bounds__(256) void phase_d(
    const int* __restrict__ endp, const int* __restrict__ order,
    const float* __restrict__ x, float* __restrict__ out)
{
    __shared__ int   ord_sh[4][CAP];
    __shared__ float tile[32][68];
    int blk  = blockIdx.x;                 // 0 .. 2499
    int b    = blk / (NVOX/32);            // 1250 blocks per batch
    int xy0  = (blk % (NVOX/32)) * 32;
    int wv   = threadIdx.x >> 6;           // 0..3
    int lane = threadIdx.x & 63;
    int seg0 = b * NVOX + xy0 + wv * 8;    // this wave's first voxel

    // lane j<9 loads boundary end[seg0-1+j]; e[v]=begin of voxel v, e[v+1]=end
    int e = 0;
    if (lane < 9) {
        int idx = seg0 - 1 + lane;
        e = (idx >= 0) ? endp[idx] : 0;
    }
    int eb0 = __shfl(e,0), eb1 = __shfl(e,1), eb2 = __shfl(e,2),
        eb3 = __shfl(e,3), eb4 = __shfl(e,4), eb5 = __shfl(e,5),
        eb6 = __shfl(e,6), eb7 = __shfl(e,7), eb8 = __shfl(e,8);
    int count = eb8 - eb0;

    int g = lane >> 4;                     // point subgroup 0..3
    int q = (lane & 15) * 4;               // channel base for this lane

    float4 A0 = make_float4(0.f,0.f,0.f,0.f), A1 = A0, A2 = A0, A3 = A0,
           A4 = A0, A5 = A0, A6 = A0, A7 = A0;

    if (count <= CAP) {                    // ~always (avg 66, CAP=512)
        // stage: coalesced order[] load + voxel-local tag in bits 24+
        for (int i = lane; i < count; i += 64) {
            int gi  = eb0 + i;
            int pid = order[gi];
            int v = (gi >= eb1) + (gi >= eb2) + (gi >= eb3) + (gi >= eb4)
                  + (gi >= eb5) + (gi >= eb6) + (gi >= eb7);
            ord_sh[wv][i] = pid | (v << 24);
        }
        // wave-private LDS RAW: DS pipe is in-order per wave; compiler
        // inserts lgkmcnt. No block barrier needed here.

        // flat independent stream, 4-wide per subgroup (16 points/wave在flight)
        int i = g;
        for (; i + 12 < count; i += 16) {
            int w0 = ord_sh[wv][i];
            int w1 = ord_sh[wv][i + 4];
            int w2 = ord_sh[wv][i + 8];
            int w3 = ord_sh[wv][i + 12];
            const float4 a0 = *(const float4*)(x + (long)(w0 & 0xFFFFFF) * Cc + q);
            const float4 a1 = *(const float4*)(x + (long)(w1 & 0xFFFFFF) * Cc + q);
            const float4 a2 = *(const float4*)(x + (long)(w2 & 0xFFFFFF) * Cc + q);
            const float4 a3 = *(const float4*)(x + (long)(w3 & 0xFFFFFF) * Cc + q);
            { int v_ = w0 >> 24; ACC8(v_, a0); }
            { int v_ = w1 >> 24; ACC8(v_, a1); }
            { int v_ = w2 >> 24; ACC8(v_, a2); }
            { int v_ = w3 >> 24; ACC8(v_, a3); }
        }
        for (; i < count; i += 4) {
            int w = ord_sh[wv][i];
            const float4 a = *(const float4*)(x + (long)(w & 0xFFFFFF) * Cc + q);
            int v_ = w >> 24;
            ACC8(v_, a);
        }
    } else {                               // fallback: per-voxel global gather
        for (int v = 0; v < 8; ++v) {
            int begin = __shfl(e, v);
            int endv  = __shfl(e, v + 1);
            float4 sum = make_float4(0.f, 0.f, 0.f, 0.f);
            for (int t = begin + g; t < endv; t += 4) {
                int p0 = order[t];
                const float4 a0 = *(const float4*)(x + (long)p0 * Cc + q);
                sum.x += a0.x; sum.y += a0.y; sum.z += a0.z; sum.w += a0.w;
            }
            ACC8(v, sum);
        }
    }

    // cross-subgroup reduce; lanes g==0 hold finals for channels q..q+3
    RED4(A0); RED4(A1); RED4(A2); RED4(A3);
    RED4(A4); RED4(A5); RED4(A6); RED4(A7);
    if (g == 0) {
        *(float4*)&tile[wv*8 + 0][q] = A0;
        *(float4*)&tile[wv*8 + 1][q] = A1;
        *(float4*)&tile[wv*8 + 2][q] = A2;
        *(float4*)&tile[wv*8 + 3][q] = A3;
        *(float4*)&tile[wv*8 + 4][q] = A4;
        *(float4*)&tile[wv*8 + 5][q] = A5;
        *(float4*)&tile[wv*8 + 6][q] = A6;
        *(float4*)&tile[wv*8 + 7][q] = A7;
    }
    __syncthreads();

    // out[b][c][xy0+xy]: iteration s writes 8 channels x 32 xy
    float* dst = out + (long)b * Cc * NVOX + xy0;
    int xy = threadIdx.x & 31;
    int c0 = threadIdx.x >> 5;             // 0..7
    #pragma unroll
    for (int s = 0; s < 8; ++s) {
        int c = s * 8 + c0;
        dst[(long)c * NVOX + xy] = tile[xy][c];
    }
}

// ---------------------------------------------------------------------------
// Fallback (r1 atomic path) if ws is unexpectedly small
// ---------------------------------------------------------------------------
__global__ __launch_bounds__(256) void fiery_scatter_direct(
    const float* __restrict__ x, const float* __restrict__ geom,
    float* __restrict__ out)
{
    int wid  = blockIdx.x * 4 + (threadIdx.x >> 6);
    int lane = threadIdx.x & 63;
    if (wid >= TOTP) return;
    long gb = (long)wid * 3;
    float gx = geom[gb+0], gy = geom[gb+1], gz = geom[gb+2];
    int vx = (int)((gx + 50.0f) / 0.5f);
    int vy = (int)((gy + 50.0f) / 0.5f);
    int vz = (int)((gz + 10.0f) / 20.0f);
    if (!(vx >= 0 && vx < Xd && vy >= 0 && vy < Yd && vz == 0)) return;
    int b = (wid >= NP) ? 1 : 0;
    float vv = x[(long)wid * Cc + lane];
    long dst = ((long)(b * Cc + lane)) * NVOX + (vx * Yd + vy);
    atomicAdd(&out[dst], vv);
}

extern "C" void kernel_launch(void* const* d_in, const int* in_sizes, int n_in,
                              void* d_out, int out_size, void* d_ws, size_t ws_size,
                              hipStream_t stream)
{
    const float* x    = (const float*)d_in[0];
    const float* geom = (const float*)d_in[1];
    float* out = (float*)d_out;

    // ws layout: rank[TOTP] | order[TOTP] | cnt[NSEG] | start[NSEG] | bsum[128]
    size_t need = ((size_t)TOTP * 2 + (size_t)NSEG * 2 + 128) * sizeof(int);
    if (ws_size >= need) {
        int* rank  = (int*)d_ws;
        int* order = rank  + TOTP;
        int* cnt   = order + TOTP;
        int* start = cnt   + NSEG;
        int* bsum  = start + NSEG;

        zero_cnt<<<NB1, 1024, 0, stream>>>(cnt);
        phase_a<<<TOTP/256, 256, 0, stream>>>(geom, rank, cnt);
        scan_p1<<<NB1, 1024, 0, stream>>>(cnt, start, bsum);
        scan_p2<<<1, 128, 0, stream>>>(bsum);
        scan_p3<<<NB1, 1024, 0, stream>>>(start, bsum);
        phase_c<<<TOTP/256, 256, 0, stream>>>(rank, start, order);
        phase_d<<<Bq*(NVOX/32), 256, 0, stream>>>(start, order, x, out);
    } else {
        hipMemsetAsync(out, 0, (size_t)out_size * sizeof(float), stream);
        fiery_scatter_direct<<<TOTP/4, 256, 0, stream>>>(x, geom, out);
    }
}